// Round 9
// baseline (47.834 us; speedup 1.0000x reference)
//
#include <hip/hip_runtime.h>
#include <math.h>

#define F 1024
#define D 64
#define H 128

typedef float v2f __attribute__((ext_vector_type(2)));
typedef int v2i __attribute__((ext_vector_type(2)));

// Prep: A[i][k] = sum_r node[i][r]*W1[r][k] + b1[k]
//       Bt[k][i] = sum_r node[i][r]*W1[64+r][k]   (transposed for coalesced hot-loop reads)
__global__ __launch_bounds__(128) void prep_kernel(
    const float* __restrict__ node, const float* __restrict__ W1,
    const float* __restrict__ b1,
    float* __restrict__ A, float* __restrict__ Bt) {
  const int i = blockIdx.x;
  const int k = threadIdx.x;  // 0..127
  __shared__ float n[D];
  if (k < D) n[k] = node[i * D + k];
  __syncthreads();
  float a = b1[k];
  float b = 0.f;
#pragma unroll
  for (int r = 0; r < D; ++r) {
    const float nv = n[r];
    a = fmaf(nv, W1[r * H + k], a);
    b = fmaf(nv, W1[(D + r) * H + k], b);
  }
  A[i * H + k] = a;
  Bt[k * F + i] = b;
}

// Pair kernel: block = 2 output rows, 512 threads; thread owns j=2tid,2tid+1
// packed as v2f.  Issue-cycle model (R8 post-mortem): trans ops block the
// SIMD issue pipe ~16cy each and dominated 64% of cycles.  This round
// replaces v_rcp with magic+2-step-Newton (all v_pk_* full-rate ops):
//   sigma = 1/(1+exp2(arg));  y0 = bitcast(0x7EF127EA - bits(d));
//   y <- y*(2 - d*y) twice    (rel err ~1.4e-6)
// gelu_tanh(x) = x * sigma(x*(C1 + C2*x^2)), C1=-2*sqrt(2/pi)*log2(e),
// C2=C1*0.044715.  logits[i,j] = sum_k w2[k]*gelu(A[i,k]+Bt[k,j]);
// b2 cancels in softmax.  w2[k] read as uniform global -> s_load (scalar pipe).
#define C1 (-2.3022082f)
#define C2 (-0.10294323f)

__device__ __forceinline__ void gelu_acc_pk(float a, v2f b, float wk, v2f& acc) {
  const v2f X = a + b;                                    // v_pk_add
  const v2f U = X * X;                                    // v_pk_mul
  const v2f P = __builtin_elementwise_fma((v2f)(C2), U, (v2f)(C1));
  const v2f Arg = X * P;                                  // v_pk_mul
  v2f E;
  E.x = __builtin_amdgcn_exp2f(Arg.x);                    // v_exp_f32 (trans)
  E.y = __builtin_amdgcn_exp2f(Arg.y);                    // v_exp_f32 (trans)
  const v2f Dn = 1.0f + E;                                // v_pk_add
  // magic reciprocal + 2 Newton steps (no v_rcp)
  const v2i db = __builtin_bit_cast(v2i, Dn);
  v2f y = __builtin_bit_cast(v2f, (v2i)(0x7EF127EA) - db);
  v2f t = __builtin_elementwise_fma(-Dn, y, (v2f)(2.0f));
  y = y * t;
  t = __builtin_elementwise_fma(-Dn, y, (v2f)(2.0f));
  y = y * t;
  const v2f WX = wk * X;                                  // v_pk_mul
  acc = __builtin_elementwise_fma(WX, y, acc);            // v_pk_fma
}

__global__ __launch_bounds__(512) void pair_kernel(
    const float* __restrict__ A, const float* __restrict__ Bt,
    const float* __restrict__ w2, float* __restrict__ out) {
  const int i0 = blockIdx.x * 2;
  const int tid = threadIdx.x;

  __shared__ float2 sA[H];  // (A[i0][k], A[i0+1][k])
  __shared__ float redm[8][2];
  __shared__ float reds[8][2];

  if (tid < H)
    sA[tid] = make_float2(A[i0 * H + tid], A[(i0 + 1) * H + tid]);
  __syncthreads();

  v2f acc0 = {0.f, 0.f};  // row i0,   j = 2tid, 2tid+1
  v2f acc1 = {0.f, 0.f};  // row i0+1, j = 2tid, 2tid+1

  const v2f* bp = reinterpret_cast<const v2f*>(Bt) + tid;  // Bt[k][2*tid..]
#pragma unroll 8
  for (int k = 0; k < H; ++k) {
    const v2f b = bp[k * (F / 2)];
    const float2 a2 = sA[k];
    const float wk = w2[k];  // uniform -> s_load, scalar pipe
    gelu_acc_pk(a2.x, b, wk, acc0);
    gelu_acc_pk(a2.y, b, wk, acc1);
  }

  // ---- fused softmax per row (1024 logits each, 8 waves) ----
  const int wave = tid >> 6;
  const int lane = tid & 63;

  float m0 = fmaxf(acc0.x, acc0.y);
  float m1 = fmaxf(acc1.x, acc1.y);
#pragma unroll
  for (int off = 32; off >= 1; off >>= 1) {
    m0 = fmaxf(m0, __shfl_xor(m0, off, 64));
    m1 = fmaxf(m1, __shfl_xor(m1, off, 64));
  }
  if (lane == 0) {
    redm[wave][0] = m0;
    redm[wave][1] = m1;
  }
  __syncthreads();
  m0 = redm[0][0];
  m1 = redm[0][1];
#pragma unroll
  for (int w = 1; w < 8; ++w) {
    m0 = fmaxf(m0, redm[w][0]);
    m1 = fmaxf(m1, redm[w][1]);
  }

  float e00 = __expf(acc0.x - m0);
  float e01 = __expf(acc0.y - m0);
  float e10 = __expf(acc1.x - m1);
  float e11 = __expf(acc1.y - m1);
  float s0 = e00 + e01;
  float s1 = e10 + e11;
#pragma unroll
  for (int off = 32; off >= 1; off >>= 1) {
    s0 += __shfl_xor(s0, off, 64);
    s1 += __shfl_xor(s1, off, 64);
  }
  if (lane == 0) {
    reds[wave][0] = s0;
    reds[wave][1] = s1;
  }
  __syncthreads();
  s0 = 0.f;
  s1 = 0.f;
#pragma unroll
  for (int w = 0; w < 8; ++w) {
    s0 += reds[w][0];
    s1 += reds[w][1];
  }

  const float inv0 = __builtin_amdgcn_rcpf(s0);
  const float inv1 = __builtin_amdgcn_rcpf(s1);
  float2 o0, o1;
  o0.x = e00 * inv0;
  o0.y = e01 * inv0;
  o1.x = e10 * inv1;
  o1.y = e11 * inv1;
  *reinterpret_cast<float2*>(out + (size_t)i0 * F + 2 * tid) = o0;
  *reinterpret_cast<float2*>(out + (size_t)(i0 + 1) * F + 2 * tid) = o1;
}

extern "C" void kernel_launch(void* const* d_in, const int* in_sizes, int n_in,
                              void* d_out, int out_size, void* d_ws, size_t ws_size,
                              hipStream_t stream) {
  const float* node = (const float*)d_in[0];  // [1024,64]
  const float* W1   = (const float*)d_in[1];  // [128,128]
  const float* b1   = (const float*)d_in[2];  // [128]
  const float* w2   = (const float*)d_in[3];  // [128]
  // d_in[4] = b2 : cancels in softmax, unused
  float* out = (float*)d_out;                 // [1024,1024]

  float* A  = (float*)d_ws;                   // [1024][128] = 512 KB
  float* Bt = A + (size_t)F * H;              // [128][1024] = 512 KB

  prep_kernel<<<F, H, 0, stream>>>(node, W1, b1, A, Bt);
  pair_kernel<<<F / 2, 512, 0, stream>>>(A, Bt, w2, out);
}

// Round 10
// 47.707 us; speedup vs baseline: 1.0027x; 1.0027x over previous
//
#include <hip/hip_runtime.h>
#include <math.h>

#define F 1024
#define D 64
#define H 128
#define BK 8                      // k-rows per staged tile (32 KB)
#define NT (H / BK)               // 16 tiles

typedef float v2f __attribute__((ext_vector_type(2)));

// Prep: A[i][k] = sum_r node[i][r]*W1[r][k] + b1[k]
//       Bt[k][i] = sum_r node[i][r]*W1[64+r][k]   (transposed; rows contiguous
//       so a BK-row tile is one 32 KB contiguous block for global_load_lds)
__global__ __launch_bounds__(128) void prep_kernel(
    const float* __restrict__ node, const float* __restrict__ W1,
    const float* __restrict__ b1,
    float* __restrict__ A, float* __restrict__ Bt) {
  const int i = blockIdx.x;
  const int k = threadIdx.x;  // 0..127
  __shared__ float n[D];
  if (k < D) n[k] = node[i * D + k];
  __syncthreads();
  float a = b1[k];
  float b = 0.f;
#pragma unroll
  for (int r = 0; r < D; ++r) {
    const float nv = n[r];
    a = fmaf(nv, W1[r * H + k], a);
    b = fmaf(nv, W1[(D + r) * H + k], b);
  }
  A[i * H + k] = a;
  Bt[k * F + i] = b;
}

// gelu_tanh(x) = x * rcp(1 + exp2(x * (C1 + C2*x^2)))   (R6 math, bit-identical)
// C1 = -2*sqrt(2/pi)*log2(e), C2 = C1*0.044715.
#define C1 (-2.3022082f)
#define C2 (-0.10294323f)

__device__ __forceinline__ void gelu_acc_pk(float a, v2f b, float wk, v2f& acc) {
  const v2f X = a + b;
  const v2f U = X * X;
  const v2f P = __builtin_elementwise_fma((v2f)(C2), U, (v2f)(C1));
  const v2f Arg = X * P;
  v2f E;
  E.x = __builtin_amdgcn_exp2f(Arg.x);
  E.y = __builtin_amdgcn_exp2f(Arg.y);
  const v2f Dn = 1.0f + E;
  v2f R;
  R.x = __builtin_amdgcn_rcpf(Dn.x);
  R.y = __builtin_amdgcn_rcpf(Dn.y);
  acc = __builtin_elementwise_fma(wk * X, R, acc);
}

// Pair kernel: block = 2 output rows, 512 threads (8 waves); thread owns
// j = 2tid, 2tid+1 packed as v2f.  Bt staged tile-by-tile into LDS with
// async global_load_lds (16 B/lane), double-buffered: stage tile t+1 while
// computing tile t from LDS.  Inner loop has ZERO global vector loads ->
// no per-batch vmcnt stalls (R6's ~37% idle).  __syncthreads() drains
// vmcnt; the ~960 cy of tile compute covers the ~200-400 cy load latency.
__global__ __launch_bounds__(512) void pair_kernel(
    const float* __restrict__ A, const float* __restrict__ Bt,
    const float* __restrict__ w2, float* __restrict__ out) {
  const int i0 = blockIdx.x * 2;
  const int tid = threadIdx.x;
  const int wave = tid >> 6;
  const int lane = tid & 63;

  __shared__ float bufs[2][BK * F];  // 2 x 32 KB
  __shared__ float2 sA[H];           // (A[i0][k], A[i0+1][k])
  __shared__ float redm[8][2];
  __shared__ float reds[8][2];

  if (tid < H)
    sA[tid] = make_float2(A[i0 * H + tid], A[(i0 + 1) * H + tid]);

  // Stage tile `tile` (Bt rows [tile*BK, tile*BK+BK) = 32 KB contiguous)
  // into bufs[buf].  Wave w, round r: 1 KB chunk at (r*8 + w) KB; lane
  // covers 16 B.  LDS dest is wave-uniform base (+ lane*16 by HW).
  const char* const bt_base = (const char*)Bt;
#define STAGE(buf_, tile_)                                                   \
  {                                                                          \
    const char* src_ = bt_base + (size_t)(tile_) * (BK * F * 4);             \
    _Pragma("unroll")                                                        \
    for (int r_ = 0; r_ < 4; ++r_) {                                         \
      const int chunk_ = r_ * 8192 + wave * 1024;                            \
      __builtin_amdgcn_global_load_lds(                                      \
          (const __attribute__((address_space(1))) void*)(src_ + chunk_ +    \
                                                          lane * 16),        \
          (__attribute__((address_space(3))) void*)((char*)&bufs[buf_][0] +  \
                                                    chunk_),                 \
          16, 0, 0);                                                         \
    }                                                                        \
  }

  STAGE(0, 0);
  __syncthreads();  // drains stage-0 vmcnt + publishes sA

  v2f acc0 = {0.f, 0.f};  // row i0,   j = 2tid, 2tid+1
  v2f acc1 = {0.f, 0.f};  // row i0+1, j = 2tid, 2tid+1

#define COMPUTE(buf_, tile_)                                                 \
  {                                                                          \
    const float* bb_ = &bufs[buf_][2 * tid];                                 \
    _Pragma("unroll")                                                        \
    for (int kk_ = 0; kk_ < BK; ++kk_) {                                     \
      const int k_ = (tile_)*BK + kk_;                                       \
      const v2f b_ = *(const v2f*)(bb_ + kk_ * F);                           \
      const float2 a2_ = sA[k_];                                             \
      const float wk_ = w2[k_];                                              \
      gelu_acc_pk(a2_.x, b_, wk_, acc0);                                     \
      gelu_acc_pk(a2_.y, b_, wk_, acc1);                                     \
    }                                                                        \
  }

  for (int t = 0; t < NT; t += 2) {
    // phase A: stage tile t+1 into bufs[1], compute bufs[0]
    STAGE(1, t + 1);
    COMPUTE(0, t);
    __syncthreads();
    // phase B: stage tile t+2 into bufs[0], compute bufs[1]
    if (t + 2 < NT) STAGE(0, t + 2);
    COMPUTE(1, t + 1);
    __syncthreads();
  }

  // ---- fused softmax per row (1024 logits each, 8 waves) ----
  float m0 = fmaxf(acc0.x, acc0.y);
  float m1 = fmaxf(acc1.x, acc1.y);
#pragma unroll
  for (int off = 32; off >= 1; off >>= 1) {
    m0 = fmaxf(m0, __shfl_xor(m0, off, 64));
    m1 = fmaxf(m1, __shfl_xor(m1, off, 64));
  }
  if (lane == 0) {
    redm[wave][0] = m0;
    redm[wave][1] = m1;
  }
  __syncthreads();
  m0 = redm[0][0];
  m1 = redm[0][1];
#pragma unroll
  for (int w = 1; w < 8; ++w) {
    m0 = fmaxf(m0, redm[w][0]);
    m1 = fmaxf(m1, redm[w][1]);
  }

  float e00 = __expf(acc0.x - m0);
  float e01 = __expf(acc0.y - m0);
  float e10 = __expf(acc1.x - m1);
  float e11 = __expf(acc1.y - m1);
  float s0 = e00 + e01;
  float s1 = e10 + e11;
#pragma unroll
  for (int off = 32; off >= 1; off >>= 1) {
    s0 += __shfl_xor(s0, off, 64);
    s1 += __shfl_xor(s1, off, 64);
  }
  if (lane == 0) {
    reds[wave][0] = s0;
    reds[wave][1] = s1;
  }
  __syncthreads();
  s0 = 0.f;
  s1 = 0.f;
#pragma unroll
  for (int w = 0; w < 8; ++w) {
    s0 += reds[w][0];
    s1 += reds[w][1];
  }

  const float inv0 = __builtin_amdgcn_rcpf(s0);
  const float inv1 = __builtin_amdgcn_rcpf(s1);
  float2 o0, o1;
  o0.x = e00 * inv0;
  o0.y = e01 * inv0;
  o1.x = e10 * inv1;
  o1.y = e11 * inv1;
  *reinterpret_cast<float2*>(out + (size_t)i0 * F + 2 * tid) = o0;
  *reinterpret_cast<float2*>(out + (size_t)(i0 + 1) * F + 2 * tid) = o1;
}

extern "C" void kernel_launch(void* const* d_in, const int* in_sizes, int n_in,
                              void* d_out, int out_size, void* d_ws, size_t ws_size,
                              hipStream_t stream) {
  const float* node = (const float*)d_in[0];  // [1024,64]
  const float* W1   = (const float*)d_in[1];  // [128,128]
  const float* b1   = (const float*)d_in[2];  // [128]
  const float* w2   = (const float*)d_in[3];  // [128]
  // d_in[4] = b2 : cancels in softmax, unused
  float* out = (float*)d_out;                 // [1024,1024]

  float* A  = (float*)d_ws;                   // [1024][128] = 512 KB
  float* Bt = A + (size_t)F * H;              // [128][1024] = 512 KB

  prep_kernel<<<F, H, 0, stream>>>(node, W1, b1, A, Bt);
  pair_kernel<<<F / 2, 512, 0, stream>>>(A, Bt, w2, out);
}

// Round 11
// 44.372 us; speedup vs baseline: 1.0780x; 1.0751x over previous
//
#include <hip/hip_runtime.h>
#include <math.h>

#define F 1024
#define D 64
#define H 128

typedef float v2f __attribute__((ext_vector_type(2)));

// Prep: A[i][k] = sum_r node[i][r]*W1[r][k] + b1[k]
//       Bt[k][i] = sum_r node[i][r]*W1[64+r][k]   (transposed for coalesced hot-loop reads)
__global__ __launch_bounds__(128) void prep_kernel(
    const float* __restrict__ node, const float* __restrict__ W1,
    const float* __restrict__ b1,
    float* __restrict__ A, float* __restrict__ Bt) {
  const int i = blockIdx.x;
  const int k = threadIdx.x;  // 0..127
  __shared__ float n[D];
  if (k < D) n[k] = node[i * D + k];
  __syncthreads();
  float a = b1[k];
  float b = 0.f;
#pragma unroll
  for (int r = 0; r < D; ++r) {
    const float nv = n[r];
    a = fmaf(nv, W1[r * H + k], a);
    b = fmaf(nv, W1[(D + r) * H + k], b);
  }
  A[i * H + k] = a;
  Bt[k * F + i] = b;
}

// Pair kernel (R6 structure): block = 2 output rows, 512 threads (8 waves);
// thread owns j = 2tid, 2tid+1 packed as v2f.
// gelu_tanh(x) = x * sigma,  sigma = rcp(1 + exp2(x*(C1 + C2*x^2)))
// PAIRED RECIPROCAL (Montgomery n=2): one v_rcp serves both packed elements:
//   r = rcp(d0*d1); sigma0 = d1*r; sigma1 = d0*r   (exact to ~2 ulp)
// Cuts trans ops/iter 8 -> 6 with only +2 short-chain full-rate ops.
// Overflow-safe for x >= -7.5 per element (pair product <= 2^121 < f32 max);
// inputs are ~N(0,1), |x|max ~ 6 over 134M samples.  Both-extreme case
// degrades benignly (inf -> r=0 -> sigma=0 = correct limit).
// C1 = -2*sqrt(2/pi)*log2(e), C2 = C1*0.044715.
// logits[i,j] = sum_k w2[k]*gelu(A[i,k]+Bt[k,j]); b2 cancels in softmax.
#define C1 (-2.3022082f)
#define C2 (-0.10294323f)

__device__ __forceinline__ void gelu_acc_pk(float a, v2f b, float wk, v2f& acc) {
  const v2f X = a + b;                                   // v_pk_add
  const v2f U = X * X;                                   // v_pk_mul
  const v2f P = __builtin_elementwise_fma((v2f)(C2), U, (v2f)(C1));
  const v2f Arg = X * P;                                 // v_pk_mul
  v2f E;
  E.x = __builtin_amdgcn_exp2f(Arg.x);                   // v_exp_f32 (trans)
  E.y = __builtin_amdgcn_exp2f(Arg.y);                   // v_exp_f32 (trans)
  const v2f Dn = 1.0f + E;                               // v_pk_add
  const float pr = Dn.x * Dn.y;                          // v_mul_f32
  const float r = __builtin_amdgcn_rcpf(pr);             // v_rcp_f32 (trans, shared)
  const v2f Dsw = {Dn.y, Dn.x};                          // opsel swap
  const v2f S = Dsw * r;                                 // v_pk_mul -> {1/d0, 1/d1}
  acc = __builtin_elementwise_fma(wk * X, S, acc);       // v_pk_mul + v_pk_fma
}

__global__ __launch_bounds__(512) void pair_kernel(
    const float* __restrict__ A, const float* __restrict__ Bt,
    const float* __restrict__ w2, float* __restrict__ out) {
  const int i0 = blockIdx.x * 2;
  const int tid = threadIdx.x;

  __shared__ float4 sAW[H];  // (A[i0][k], A[i0+1][k], w2[k], 0)
  __shared__ float redm[8][2];
  __shared__ float reds[8][2];

  if (tid < H)
    sAW[tid] = make_float4(A[i0 * H + tid], A[(i0 + 1) * H + tid], w2[tid], 0.f);
  __syncthreads();

  v2f acc0 = {0.f, 0.f};  // row i0,   j = 2tid, 2tid+1
  v2f acc1 = {0.f, 0.f};  // row i0+1, j = 2tid, 2tid+1

  const v2f* bp = reinterpret_cast<const v2f*>(Bt) + tid;  // Bt[k][2*tid..]
#pragma unroll 8
  for (int k = 0; k < H; ++k) {
    const v2f b = bp[k * (F / 2)];
    const float4 aw = sAW[k];
    gelu_acc_pk(aw.x, b, aw.z, acc0);
    gelu_acc_pk(aw.y, b, aw.z, acc1);
  }

  // ---- fused softmax per row (1024 logits each, 8 waves) ----
  const int wave = tid >> 6;
  const int lane = tid & 63;

  float m0 = fmaxf(acc0.x, acc0.y);
  float m1 = fmaxf(acc1.x, acc1.y);
#pragma unroll
  for (int off = 32; off >= 1; off >>= 1) {
    m0 = fmaxf(m0, __shfl_xor(m0, off, 64));
    m1 = fmaxf(m1, __shfl_xor(m1, off, 64));
  }
  if (lane == 0) {
    redm[wave][0] = m0;
    redm[wave][1] = m1;
  }
  __syncthreads();
  m0 = redm[0][0];
  m1 = redm[0][1];
#pragma unroll
  for (int w = 1; w < 8; ++w) {
    m0 = fmaxf(m0, redm[w][0]);
    m1 = fmaxf(m1, redm[w][1]);
  }

  float e00 = __expf(acc0.x - m0);
  float e01 = __expf(acc0.y - m0);
  float e10 = __expf(acc1.x - m1);
  float e11 = __expf(acc1.y - m1);
  float s0 = e00 + e01;
  float s1 = e10 + e11;
#pragma unroll
  for (int off = 32; off >= 1; off >>= 1) {
    s0 += __shfl_xor(s0, off, 64);
    s1 += __shfl_xor(s1, off, 64);
  }
  if (lane == 0) {
    reds[wave][0] = s0;
    reds[wave][1] = s1;
  }
  __syncthreads();
  s0 = 0.f;
  s1 = 0.f;
#pragma unroll
  for (int w = 0; w < 8; ++w) {
    s0 += reds[w][0];
    s1 += reds[w][1];
  }

  const float inv0 = __builtin_amdgcn_rcpf(s0);
  const float inv1 = __builtin_amdgcn_rcpf(s1);
  float2 o0, o1;
  o0.x = e00 * inv0;
  o0.y = e01 * inv0;
  o1.x = e10 * inv1;
  o1.y = e11 * inv1;
  *reinterpret_cast<float2*>(out + (size_t)i0 * F + 2 * tid) = o0;
  *reinterpret_cast<float2*>(out + (size_t)(i0 + 1) * F + 2 * tid) = o1;
}

extern "C" void kernel_launch(void* const* d_in, const int* in_sizes, int n_in,
                              void* d_out, int out_size, void* d_ws, size_t ws_size,
                              hipStream_t stream) {
  const float* node = (const float*)d_in[0];  // [1024,64]
  const float* W1   = (const float*)d_in[1];  // [128,128]
  const float* b1   = (const float*)d_in[2];  // [128]
  const float* w2   = (const float*)d_in[3];  // [128]
  // d_in[4] = b2 : cancels in softmax, unused
  float* out = (float*)d_out;                 // [1024,1024]

  float* A  = (float*)d_ws;                   // [1024][128] = 512 KB
  float* Bt = A + (size_t)F * H;              // [128][1024] = 512 KB

  prep_kernel<<<F, H, 0, stream>>>(node, W1, b1, A, Bt);
  pair_kernel<<<F / 2, 512, 0, stream>>>(A, Bt, w2, out);
}

// Round 12
// 44.281 us; speedup vs baseline: 1.0802x; 1.0021x over previous
//
#include <hip/hip_runtime.h>
#include <math.h>

#define F 1024
#define D 64
#define H 128

typedef float v2f __attribute__((ext_vector_type(2)));

// Prep: A[i][k] = sum_r node[i][r]*W1[r][k] + b1[k]
//       Bt[k][i] = sum_r node[i][r]*W1[64+r][k]   (transposed for coalesced hot-loop reads)
__global__ __launch_bounds__(128) void prep_kernel(
    const float* __restrict__ node, const float* __restrict__ W1,
    const float* __restrict__ b1,
    float* __restrict__ A, float* __restrict__ Bt) {
  const int i = blockIdx.x;
  const int k = threadIdx.x;  // 0..127
  __shared__ float n[D];
  if (k < D) n[k] = node[i * D + k];
  __syncthreads();
  float a = b1[k];
  float b = 0.f;
#pragma unroll
  for (int r = 0; r < D; ++r) {
    const float nv = n[r];
    a = fmaf(nv, W1[r * H + k], a);
    b = fmaf(nv, W1[(D + r) * H + k], b);
  }
  A[i * H + k] = a;
  Bt[k * F + i] = b;
}

// Pair kernel (R6 math, bit-compatible): block = 2 output rows, 512 threads
// (8 waves); thread owns j = 2tid, 2tid+1 packed as v2f.
// R12 changes vs R6:
//  1. NO LDS in hot loop: A-row and w2 values are wave-uniform -> read from
//     global with uniform indices so the compiler emits s_load (scalar pipe,
//     scalar cache). Removes per-iter ds_read_b128 + lgkmcnt wait.
//  2. Wave de-phasing: wave wv starts its k-loop at k0 = wv*16 (mod 128).
//     Lockstep waves demand the same pipe (VALU vs trans) simultaneously;
//     rotation mixes phases per SIMD. fp32 reassociation only (sum of the
//     same 128 terms) -> absmax stays ~1.5e-5.
// gelu_tanh(x) = x * rcp(1 + exp2(x * (C1 + C2*x^2)))
// C1 = -2*sqrt(2/pi)*log2(e), C2 = C1*0.044715.
// logits[i,j] = sum_k w2[k] * gelu(A[i,k] + Bt[k,j]); b2 cancels in softmax.
#define C1 (-2.3022082f)
#define C2 (-0.10294323f)

__device__ __forceinline__ void gelu_acc_pk(float a, v2f b, float wk, v2f& acc) {
  const v2f X = a + b;                                   // v_pk_add (sgpr splat)
  const v2f U = X * X;                                   // v_pk_mul
  const v2f P = __builtin_elementwise_fma((v2f)(C2), U, (v2f)(C1));
  const v2f Arg = X * P;                                 // v_pk_mul
  v2f E;
  E.x = __builtin_amdgcn_exp2f(Arg.x);                   // v_exp_f32 (trans)
  E.y = __builtin_amdgcn_exp2f(Arg.y);                   // v_exp_f32 (trans)
  const v2f Dn = 1.0f + E;                               // v_pk_add
  v2f R;
  R.x = __builtin_amdgcn_rcpf(Dn.x);                     // v_rcp_f32 (trans)
  R.y = __builtin_amdgcn_rcpf(Dn.y);                     // v_rcp_f32 (trans)
  acc = __builtin_elementwise_fma(wk * X, R, acc);       // v_pk_mul + v_pk_fma
}

__global__ __launch_bounds__(512) void pair_kernel(
    const float* __restrict__ A, const float* __restrict__ Bt,
    const float* __restrict__ w2, float* __restrict__ out) {
  const int i0 = blockIdx.x * 2;
  const int tid = threadIdx.x;

  __shared__ float redm[8][2];
  __shared__ float reds[8][2];

  // wave id as a provably wave-uniform (SGPR) value
  const int wv = __builtin_amdgcn_readfirstlane(tid) >> 6;
  const int lane = tid & 63;

  const float* __restrict__ Arow0 = A + (size_t)i0 * H;
  const float* __restrict__ Arow1 = Arow0 + H;

  v2f acc0 = {0.f, 0.f};  // row i0,   j = 2tid, 2tid+1
  v2f acc1 = {0.f, 0.f};  // row i0+1, j = 2tid, 2tid+1

  const v2f* bp = reinterpret_cast<const v2f*>(Bt) + tid;  // Bt[k][2*tid..]
  const int k0 = wv << 4;  // per-wave rotation: 0,16,...,112
#pragma unroll 8
  for (int kk = 0; kk < H; ++kk) {
    const int k = (kk + k0) & (H - 1);         // uniform (scalar ALU)
    const v2f b = bp[k * (F / 2)];
    const float a0 = Arow0[k];                 // uniform -> s_load
    const float a1 = Arow1[k];                 // uniform -> s_load
    const float wk = w2[k];                    // uniform -> s_load
    gelu_acc_pk(a0, b, wk, acc0);
    gelu_acc_pk(a1, b, wk, acc1);
  }

  // ---- fused softmax per row (1024 logits each, 8 waves) ----
  float m0 = fmaxf(acc0.x, acc0.y);
  float m1 = fmaxf(acc1.x, acc1.y);
#pragma unroll
  for (int off = 32; off >= 1; off >>= 1) {
    m0 = fmaxf(m0, __shfl_xor(m0, off, 64));
    m1 = fmaxf(m1, __shfl_xor(m1, off, 64));
  }
  if (lane == 0) {
    redm[wv][0] = m0;
    redm[wv][1] = m1;
  }
  __syncthreads();
  m0 = redm[0][0];
  m1 = redm[0][1];
#pragma unroll
  for (int w = 1; w < 8; ++w) {
    m0 = fmaxf(m0, redm[w][0]);
    m1 = fmaxf(m1, redm[w][1]);
  }

  float e00 = __expf(acc0.x - m0);
  float e01 = __expf(acc0.y - m0);
  float e10 = __expf(acc1.x - m1);
  float e11 = __expf(acc1.y - m1);
  float s0 = e00 + e01;
  float s1 = e10 + e11;
#pragma unroll
  for (int off = 32; off >= 1; off >>= 1) {
    s0 += __shfl_xor(s0, off, 64);
    s1 += __shfl_xor(s1, off, 64);
  }
  if (lane == 0) {
    reds[wv][0] = s0;
    reds[wv][1] = s1;
  }
  __syncthreads();
  s0 = 0.f;
  s1 = 0.f;
#pragma unroll
  for (int w = 0; w < 8; ++w) {
    s0 += reds[w][0];
    s1 += reds[w][1];
  }

  const float inv0 = __builtin_amdgcn_rcpf(s0);
  const float inv1 = __builtin_amdgcn_rcpf(s1);
  float2 o0, o1;
  o0.x = e00 * inv0;
  o0.y = e01 * inv0;
  o1.x = e10 * inv1;
  o1.y = e11 * inv1;
  *reinterpret_cast<float2*>(out + (size_t)i0 * F + 2 * tid) = o0;
  *reinterpret_cast<float2*>(out + (size_t)(i0 + 1) * F + 2 * tid) = o1;
}

extern "C" void kernel_launch(void* const* d_in, const int* in_sizes, int n_in,
                              void* d_out, int out_size, void* d_ws, size_t ws_size,
                              hipStream_t stream) {
  const float* node = (const float*)d_in[0];  // [1024,64]
  const float* W1   = (const float*)d_in[1];  // [128,128]
  const float* b1   = (const float*)d_in[2];  // [128]
  const float* w2   = (const float*)d_in[3];  // [128]
  // d_in[4] = b2 : cancels in softmax, unused
  float* out = (float*)d_out;                 // [1024,1024]

  float* A  = (float*)d_ws;                   // [1024][128] = 512 KB
  float* Bt = A + (size_t)F * H;              // [128][1024] = 512 KB

  prep_kernel<<<F, H, 0, stream>>>(node, W1, b1, A, Bt);
  pair_kernel<<<F / 2, 512, 0, stream>>>(A, Bt, w2, out);
}

// Round 13
// 44.017 us; speedup vs baseline: 1.0867x; 1.0060x over previous
//
#include <hip/hip_runtime.h>
#include <math.h>

#define F 1024
#define D 64
#define H 128

typedef float v2f __attribute__((ext_vector_type(2)));

// Prep: A[i][k] = sum_r node[i][r]*W1[r][k] + b1[k]
//       Bt[k][i] = sum_r node[i][r]*W1[64+r][k]   (transposed for coalesced hot-loop reads)
__global__ __launch_bounds__(128) void prep_kernel(
    const float* __restrict__ node, const float* __restrict__ W1,
    const float* __restrict__ b1,
    float* __restrict__ A, float* __restrict__ Bt) {
  const int i = blockIdx.x;
  const int k = threadIdx.x;  // 0..127
  __shared__ float n[D];
  if (k < D) n[k] = node[i * D + k];
  __syncthreads();
  float a = b1[k];
  float b = 0.f;
#pragma unroll
  for (int r = 0; r < D; ++r) {
    const float nv = n[r];
    a = fmaf(nv, W1[r * H + k], a);
    b = fmaf(nv, W1[(D + r) * H + k], b);
  }
  A[i * H + k] = a;
  Bt[k * F + i] = b;
}

// Pair kernel: block = 2 output rows, 512 threads (8 waves); thread owns
// j = 2tid, 2tid+1 packed as v2f; A/w2 read via uniform s_load (R12).
// CROSS-ROW MONTGOMERY RECIPROCAL (no component swaps, unlike R11):
//   D0, D1 are the sigmoid denominators of row0/row1 in MATCHING lanes.
//   PR = D0*D1; R = rcp(PR); S0 = D1*R = 1/D0; S1 = D0*R = 1/D1.
// Per k-iter: 15 pk + 6 trans (was 14 pk + 8 trans). All added ops are
// full-width v_pk_*; exact to ~2 ulp; PR <= 2^41 (x >= -8 per element,
// inputs ~N(0,1.4)) - no overflow.
// gelu_tanh(x) = x * rcp(1 + exp2(x * (C1 + C2*x^2)))
// C1 = -2*sqrt(2/pi)*log2(e), C2 = C1*0.044715.
// logits[i,j] = sum_k w2[k]*gelu(A[i,k]+Bt[k,j]); b2 cancels in softmax.
#define C1 (-2.3022082f)
#define C2 (-0.10294323f)

__device__ __forceinline__ void gelu2_acc(float a0, float a1, v2f b, float wk,
                                          v2f& acc0, v2f& acc1) {
  const v2f X0 = a0 + b;                                  // v_pk_add
  const v2f X1 = a1 + b;                                  // v_pk_add
  const v2f U0 = X0 * X0;                                 // v_pk_mul
  const v2f U1 = X1 * X1;                                 // v_pk_mul
  const v2f P0 = __builtin_elementwise_fma((v2f)(C2), U0, (v2f)(C1));
  const v2f P1 = __builtin_elementwise_fma((v2f)(C2), U1, (v2f)(C1));
  const v2f Arg0 = X0 * P0;                               // v_pk_mul
  const v2f Arg1 = X1 * P1;                               // v_pk_mul
  v2f E0, E1;
  E0.x = __builtin_amdgcn_exp2f(Arg0.x);                  // v_exp_f32
  E0.y = __builtin_amdgcn_exp2f(Arg0.y);                  // v_exp_f32
  E1.x = __builtin_amdgcn_exp2f(Arg1.x);                  // v_exp_f32
  E1.y = __builtin_amdgcn_exp2f(Arg1.y);                  // v_exp_f32
  const v2f D0 = 1.0f + E0;                               // v_pk_add
  const v2f D1 = 1.0f + E1;                               // v_pk_add
  const v2f PR = D0 * D1;                                 // v_pk_mul
  v2f R;
  R.x = __builtin_amdgcn_rcpf(PR.x);                      // v_rcp_f32
  R.y = __builtin_amdgcn_rcpf(PR.y);                      // v_rcp_f32
  const v2f S0 = D1 * R;                                  // v_pk_mul -> 1/D0
  const v2f S1 = D0 * R;                                  // v_pk_mul -> 1/D1
  acc0 = __builtin_elementwise_fma(wk * X0, S0, acc0);    // pk_mul + pk_fma
  acc1 = __builtin_elementwise_fma(wk * X1, S1, acc1);    // pk_mul + pk_fma
}

__global__ __launch_bounds__(512) void pair_kernel(
    const float* __restrict__ A, const float* __restrict__ Bt,
    const float* __restrict__ w2, float* __restrict__ out) {
  const int i0 = blockIdx.x * 2;
  const int tid = threadIdx.x;

  __shared__ float redm[8][2];
  __shared__ float reds[8][2];

  const int wv = tid >> 6;
  const int lane = tid & 63;

  const float* __restrict__ Arow0 = A + (size_t)i0 * H;
  const float* __restrict__ Arow1 = Arow0 + H;

  v2f acc0 = {0.f, 0.f};  // row i0,   j = 2tid, 2tid+1
  v2f acc1 = {0.f, 0.f};  // row i0+1, j = 2tid, 2tid+1

  const v2f* bp = reinterpret_cast<const v2f*>(Bt) + tid;  // Bt[k][2*tid..]
#pragma unroll 8
  for (int k = 0; k < H; ++k) {
    const v2f b = bp[k * (F / 2)];
    const float a0 = Arow0[k];   // uniform -> s_load
    const float a1 = Arow1[k];   // uniform -> s_load
    const float wk = w2[k];      // uniform -> s_load
    gelu2_acc(a0, a1, b, wk, acc0, acc1);
  }

  // ---- fused softmax per row (1024 logits each, 8 waves) ----
  float m0 = fmaxf(acc0.x, acc0.y);
  float m1 = fmaxf(acc1.x, acc1.y);
#pragma unroll
  for (int off = 32; off >= 1; off >>= 1) {
    m0 = fmaxf(m0, __shfl_xor(m0, off, 64));
    m1 = fmaxf(m1, __shfl_xor(m1, off, 64));
  }
  if (lane == 0) {
    redm[wv][0] = m0;
    redm[wv][1] = m1;
  }
  __syncthreads();
  m0 = redm[0][0];
  m1 = redm[0][1];
#pragma unroll
  for (int w = 1; w < 8; ++w) {
    m0 = fmaxf(m0, redm[w][0]);
    m1 = fmaxf(m1, redm[w][1]);
  }

  float e00 = __expf(acc0.x - m0);
  float e01 = __expf(acc0.y - m0);
  float e10 = __expf(acc1.x - m1);
  float e11 = __expf(acc1.y - m1);
  float s0 = e00 + e01;
  float s1 = e10 + e11;
#pragma unroll
  for (int off = 32; off >= 1; off >>= 1) {
    s0 += __shfl_xor(s0, off, 64);
    s1 += __shfl_xor(s1, off, 64);
  }
  if (lane == 0) {
    reds[wv][0] = s0;
    reds[wv][1] = s1;
  }
  __syncthreads();
  s0 = 0.f;
  s1 = 0.f;
#pragma unroll
  for (int w = 0; w < 8; ++w) {
    s0 += reds[w][0];
    s1 += reds[w][1];
  }

  const float inv0 = __builtin_amdgcn_rcpf(s0);
  const float inv1 = __builtin_amdgcn_rcpf(s1);
  float2 o0, o1;
  o0.x = e00 * inv0;
  o0.y = e01 * inv0;
  o1.x = e10 * inv1;
  o1.y = e11 * inv1;
  *reinterpret_cast<float2*>(out + (size_t)i0 * F + 2 * tid) = o0;
  *reinterpret_cast<float2*>(out + (size_t)(i0 + 1) * F + 2 * tid) = o1;
}

extern "C" void kernel_launch(void* const* d_in, const int* in_sizes, int n_in,
                              void* d_out, int out_size, void* d_ws, size_t ws_size,
                              hipStream_t stream) {
  const float* node = (const float*)d_in[0];  // [1024,64]
  const float* W1   = (const float*)d_in[1];  // [128,128]
  const float* b1   = (const float*)d_in[2];  // [128]
  const float* w2   = (const float*)d_in[3];  // [128]
  // d_in[4] = b2 : cancels in softmax, unused
  float* out = (float*)d_out;                 // [1024,1024]

  float* A  = (float*)d_ws;                   // [1024][128] = 512 KB
  float* Bt = A + (size_t)F * H;              // [128][1024] = 512 KB

  prep_kernel<<<F, H, 0, stream>>>(node, W1, b1, A, Bt);
  pair_kernel<<<F / 2, 512, 0, stream>>>(A, Bt, w2, out);
}